// Round 9
// baseline (158.765 us; speedup 1.0000x reference)
//
#include <hip/hip_runtime.h>
#include <hip/hip_bf16.h>

// LFA_self — 3-kernel pipeline for MI355X (round 9).
// scores = Xq (Wq Wk^T) Xk^T + g(t2); out = attn . (Xv (Wv Wo)) + (bv Wo + bo).
// Round-9: (a) bf16 packing via single v_cvt_pk_bf16_f32 (was ~10-inst manual
// RNE per pair); (b) item-granular load pipeline: chunk-0 loads issued before
// init, next-chunk loads issued per-item right after consumption, so HBM
// latency hides under projection VALU + MFMA.

#define NT 49
#define TOKS 16384
#define HSL 1024
#define SLOT 3200            // floats per partial slot: 49x64 scores + 64 g-tail
#define ZSWZ(n) (((((n) & 7) ^ (((n) >> 3) & 7))) << 4)

typedef __attribute__((ext_vector_type(8))) short bf16x8;
typedef __attribute__((ext_vector_type(4))) float f32x4;

__device__ __forceinline__ ushort f2bf(float f) {
    union { float f; unsigned u; } v; v.f = f;
    return (ushort)((v.u + 0x7fffu + ((v.u >> 16) & 1u)) >> 16);   // RNE
}
// packed f32x2 -> bf16x2 (RNE), one instruction
__device__ __forceinline__ unsigned pk2(float lo, float hi) {
    unsigned r;
    asm("v_cvt_pk_bf16_f32 %0, %1, %2" : "=v"(r) : "v"(lo), "v"(hi));
    return r;
}
__device__ __forceinline__ float4 f4mul(float s, float4 w) {
    return make_float4(s*w.x, s*w.y, s*w.z, s*w.w);
}
__device__ __forceinline__ float4 f4fma(float s, float4 w, float4 a) {
    a.x = fmaf(s, w.x, a.x); a.y = fmaf(s, w.y, a.y);
    a.z = fmaf(s, w.z, a.z); a.w = fmaf(s, w.w, a.w);
    return a;
}
__device__ __forceinline__ float red4s(float v) {
    v += __shfl_xor(v, 1); v += __shfl_xor(v, 2); return v;
}
__device__ __forceinline__ float4 red4v(float4 v) {
    return make_float4(red4s(v.x), red4s(v.y), red4s(v.z), red4s(v.w));
}

// W preload: 16 named float4 = rows (lane&3)*4..+3 of a 16x16 row-major matrix
#define W_DECL(mb) \
    const float4 W00 = *(const float4*)((mb)+ 0), W01 = *(const float4*)((mb)+ 4), \
                 W02 = *(const float4*)((mb)+ 8), W03 = *(const float4*)((mb)+12), \
                 W10 = *(const float4*)((mb)+16), W11 = *(const float4*)((mb)+20), \
                 W12 = *(const float4*)((mb)+24), W13 = *(const float4*)((mb)+28), \
                 W20 = *(const float4*)((mb)+32), W21 = *(const float4*)((mb)+36), \
                 W22 = *(const float4*)((mb)+40), W23 = *(const float4*)((mb)+44), \
                 W30 = *(const float4*)((mb)+48), W31 = *(const float4*)((mb)+52), \
                 W32 = *(const float4*)((mb)+56), W33 = *(const float4*)((mb)+60)

#define PROJ_BFLY(a, y0, y1, y2, y3) \
    float4 y0 = f4mul((a).x, W00); y0 = f4fma((a).y, W10, y0); \
    y0 = f4fma((a).z, W20, y0);    y0 = f4fma((a).w, W30, y0); \
    float4 y1 = f4mul((a).x, W01); y1 = f4fma((a).y, W11, y1); \
    y1 = f4fma((a).z, W21, y1);    y1 = f4fma((a).w, W31, y1); \
    float4 y2 = f4mul((a).x, W02); y2 = f4fma((a).y, W12, y2); \
    y2 = f4fma((a).z, W22, y2);    y2 = f4fma((a).w, W32, y2); \
    float4 y3 = f4mul((a).x, W03); y3 = f4fma((a).y, W13, y3); \
    y3 = f4fma((a).z, W23, y3);    y3 = f4fma((a).w, W33, y3); \
    y0 = red4v(y0); y1 = red4v(y1); y2 = red4v(y2); y3 = red4v(y3)

// ===== K1: partial scores, grid (b,h,s)=512*SPLIT, 256 thr =================
template<int SPLIT, int LOG2S>
__global__ __launch_bounds__(256, 2) void k_scores(
    const float* __restrict__ qin, const float* __restrict__ kin,
    const float* __restrict__ Wq, const float* __restrict__ bq,
    const float* __restrict__ Wk, float* __restrict__ ws1)
{
    __shared__ ushort bufA[64*128];   // Yq bf16, 256B rows, XOR-swizzled
    __shared__ ushort bufB[64*128];   // Xk bf16, swizzled
    __shared__ float  Msh[256];       // Wq Wk^T
    __shared__ float  wkbqSh[16];     // Wk bq
    __shared__ float  gSh[64];

    const int tid  = threadIdx.x;
    const int lane = tid & 63;
    const int wv   = tid >> 6;        // 0..3
    const int s    = blockIdx.x & (SPLIT - 1);
    const int h    = (blockIdx.x >> LOG2S) & 15;
    const int b    = blockIdx.x >> (LOG2S + 4);

    const float* qbase = qin + (size_t)b*NT*TOKS + h*HSL + s*(1024/SPLIT);
    const float* kbase = kin + (size_t)b*NT*TOKS + h*HSL + s*(1024/SPLIT);

    const int f4 = tid & 31;          // column group (iteration-invariant)
    const int t0 = tid >> 5;          // base token row
    const int r  = f4 & 3;

    // ---- issue chunk-0 loads FIRST (latency hides under init)
    float4 qv[7], kv[7];
    {
        const float* qc = qbase + f4*4;
        const float* kp = kbase + f4*4;
        #pragma unroll
        for (int i = 0; i < 7; ++i) {
            const int t  = t0 + 8*i;
            const int tc = t < 48 ? t : 48;           // clamp: in-bounds always
            qv[i] = *(const float4*)(qc + (size_t)tc*TOKS);
            kv[i] = *(const float4*)(kp + (size_t)tc*TOKS);
        }
    }

    {   // init: zero pad rows (49..63 must be 0 for MFMA), weight products
        unsigned* z0 = (unsigned*)bufA; unsigned* z1 = (unsigned*)bufB;
        for (int i = tid; i < 4096; i += 256) { z0[i] = 0u; z1[i] = 0u; }
        const int c1 = tid >> 4, c2 = tid & 15;
        float m = 0.f;
        #pragma unroll
        for (int f = 0; f < 16; ++f) m += Wq[c1*16+f] * Wk[c2*16+f];
        Msh[tid] = m;
        if (tid < 16) {
            float wb = 0.f;
            #pragma unroll
            for (int g = 0; g < 16; ++g) wb += Wk[tid*16+g] * bq[g];
            wkbqSh[tid] = wb;
        }
        if (tid < 64) gSh[tid] = 0.f;
    }
    __syncthreads();

    const float* mb = Msh + (lane & 3)*64;     // this lane's 4 rows of M
    W_DECL(mb);

    f32x4 accS[4];
    #pragma unroll
    for (int nt = 0; nt < 4; ++nt) accS[nt] = (f32x4){0.f,0.f,0.f,0.f};

    constexpr int NC = 8 / SPLIT;
    for (int kc = 0; kc < NC; ++kc) {
        const float* qn = qbase + (kc+1)*128 + f4*4;
        const float* kn = kbase + (kc+1)*128 + f4*4;
        // ---- process current chunk; per item, refill the slot for kc+1
        #pragma unroll
        for (int i = 0; i < 7; ++i) {
            const int t  = t0 + 8*i;                  // t <= 55 < 64
            const int tc = t < 48 ? t : 48;
            float4 xq = qv[i], xk = kv[i];
            if (kc + 1 < NC) {                        // prefetch same slot
                qv[i] = *(const float4*)(qn + (size_t)tc*TOKS);
                kv[i] = *(const float4*)(kn + (size_t)tc*TOKS);
            }
            if (t >= NT) {
                xq = make_float4(0.f,0.f,0.f,0.f);
                xk = make_float4(0.f,0.f,0.f,0.f);
            }
            PROJ_BFLY(xq, y0, y1, y2, y3);
            uint2 w;
            if      (r == 0) { w.x = pk2(y0.x, y0.y); w.y = pk2(y0.z, y0.w); }
            else if (r == 1) { w.x = pk2(y1.x, y1.y); w.y = pk2(y1.z, y1.w); }
            else if (r == 2) { w.x = pk2(y2.x, y2.y); w.y = pk2(y2.z, y2.w); }
            else             { w.x = pk2(y3.x, y3.y); w.y = pk2(y3.z, y3.w); }
            const int addrA = (t*256 + (f4 >> 2)*32 + r*8) ^ ((t & 7) << 4);
            *(uint2*)((char*)bufA + addrA) = w;
            uint2 wk2; wk2.x = pk2(xk.x, xk.y); wk2.y = pk2(xk.z, xk.w);
            const int addrB = (t*256 + f4*8) ^ ((t & 7) << 4);
            *(uint2*)((char*)bufB + addrB) = wk2;
            const float* wb = wkbqSh + r*4;
            const float pg = xk.x*wb[0] + xk.y*wb[1] + xk.z*wb[2] + xk.w*wb[3];
            if (pg != 0.f) atomicAdd(&gSh[t], pg);    // bq==0 -> never fires
        }
        __syncthreads();
        #pragma unroll
        for (int ks = 0; ks < 4; ++ks) {
            const int ra  = wv*16 + (lane & 15);
            const int abo = (ra*256 + (ks*32 + (lane >> 4)*8)*2) ^ ((ra & 7) << 4);
            const bf16x8 af = *(const bf16x8*)((const char*)bufA + abo);
            #pragma unroll
            for (int nt = 0; nt < 4; ++nt) {
                const int rb  = nt*16 + (lane & 15);
                const int bbo = (rb*256 + (ks*32 + (lane >> 4)*8)*2) ^ ((rb & 7) << 4);
                const bf16x8 bf = *(const bf16x8*)((const char*)bufB + bbo);
                accS[nt] = __builtin_amdgcn_mfma_f32_16x16x32_bf16(af, bf, accS[nt], 0, 0, 0);
            }
        }
        __syncthreads();
    }

    float* slot = ws1 + (size_t)blockIdx.x * SLOT;
    #pragma unroll
    for (int nt = 0; nt < 4; ++nt) {
        const int col = nt*16 + (lane & 15);
        #pragma unroll
        for (int rr = 0; rr < 4; ++rr) {
            const int row = wv*16 + (lane >> 4)*4 + rr;
            if (row < NT) slot[row*64 + col] = accS[nt][rr];
        }
    }
    if (tid < 64) slot[3136 + tid] = gSh[tid];
}

// ===== K2: reduce + softmax, grid (b,h)=512, 256 thr =======================
template<int SPLIT>
__global__ __launch_bounds__(256, 2) void k_softmax(
    const float* __restrict__ ws1, float* __restrict__ attnp,
    ushort* __restrict__ ws2)
{
    __shared__ float sS[NT*69];
    __shared__ float sG[64];
    const int tid = threadIdx.x;
    const float* base = ws1 + (size_t)blockIdx.x * SPLIT * SLOT;

    for (int p = tid; p < 784; p += 256) {
        const int row = p >> 4, c4 = (p & 15) * 4;
        float4 acc = *(const float4*)(base + row*64 + c4);
        #pragma unroll
        for (int s = 1; s < SPLIT; ++s) {
            const float4 a = *(const float4*)(base + s*SLOT + row*64 + c4);
            acc.x += a.x; acc.y += a.y; acc.z += a.z; acc.w += a.w;
        }
        sS[row*69 + c4 + 0] = acc.x;
        sS[row*69 + c4 + 1] = acc.y;
        sS[row*69 + c4 + 2] = acc.z;
        sS[row*69 + c4 + 3] = acc.w;
    }
    if (tid < 64) {
        float g = base[3136 + tid];
        #pragma unroll
        for (int s = 1; s < SPLIT; ++s) g += base[s*SLOT + 3136 + tid];
        sG[tid] = g;
    }
    __syncthreads();

    if (tid < NT) {
        float mx = -1e30f;
        for (int j = 0; j < NT; ++j) {
            const float v = (sS[tid*69 + j] + sG[j]) * 0.03125f;
            sS[tid*69 + j] = v;
            mx = fmaxf(mx, v);
        }
        float ssum = 0.f;
        for (int j = 0; j < NT; ++j) {
            const float e = __expf(sS[tid*69 + j] - mx);
            sS[tid*69 + j] = e; ssum += e;
        }
        const float inv = 1.0f / ssum;
        for (int j = 0; j < NT; ++j) sS[tid*69 + j] *= inv;
    }
    __syncthreads();

    float* ab = attnp + (size_t)blockIdx.x * (NT*NT);
    for (int p = tid; p < NT*NT; p += 256) {
        const int t = p / NT, j = p - t*NT;
        ab[p] = sS[t*69 + j];
    }
    ushort* w2 = ws2 + (size_t)blockIdx.x * 4096;   // 64x64 bf16, zero-padded
    for (int p = tid; p < 4096; p += 256) {
        const int t = p >> 6, j = p & 63;
        const float v = (t < NT && j < NT) ? sS[t*69 + j] : 0.f;
        w2[p] = f2bf(v);
    }
}

// ===== K3: out = attn.Z + bvo, grid (b,h,kc)=4096, 256 thr =================
__global__ __launch_bounds__(256, 2) void k_out(
    const float* __restrict__ vin,
    const float* __restrict__ Wv, const float* __restrict__ bv,
    const float* __restrict__ Wo, const float* __restrict__ bo,
    const ushort* __restrict__ ws2, float* __restrict__ out)
{
    __shared__ unsigned Zt[4096];     // Z^T pair-packed: [128 n][32 kpair] u32
    __shared__ float WvoSh[256];
    __shared__ float bvoSh[16];

    const int tid  = threadIdx.x;
    const int lane = tid & 63;
    const int wv   = tid >> 6;        // 0..3 -> M-tile (token rows)
    const int kc   = blockIdx.x & 7;
    const int h    = (blockIdx.x >> 3) & 15;
    const int b    = blockIdx.x >> 7;
    const float* vbase = vin + (size_t)b*NT*TOKS + h*HSL;

    const int f4 = tid & 31;
    const int t0 = tid >> 5;          // lanes<32: even token; lanes>=32: odd
    const int r  = f4 & 3;

    // ---- issue ALL global loads first (v chunk + attn A-fragments)
    float4 vv[7];
    {
        const float* vc = vbase + kc*128 + f4*4;
        #pragma unroll
        for (int i = 0; i < 7; ++i) {
            const int t  = t0 + 8*i;
            const int tc = t < 48 ? t : 48;
            vv[i] = *(const float4*)(vc + (size_t)tc*TOKS);
        }
    }
    const ushort* w2 = ws2 + ((size_t)(blockIdx.x >> 3)) * 4096;
    const int ra = wv*16 + (lane & 15);
    const bf16x8 af0 = *(const bf16x8*)(w2 + ra*64 +      (lane >> 4)*8);
    const bf16x8 af1 = *(const bf16x8*)(w2 + ra*64 + 32 + (lane >> 4)*8);

    {
        const int c1 = tid >> 4, c2 = tid & 15;
        float wvo = 0.f;
        #pragma unroll
        for (int f = 0; f < 16; ++f) wvo += Wv[c1*16+f] * Wo[f*16+c2];
        WvoSh[tid] = wvo;
        if (tid < 16) {
            float s2 = 0.f;
            #pragma unroll
            for (int g = 0; g < 16; ++g) s2 += bv[g]*Wo[g*16+tid];
            bvoSh[tid] = s2 + bo[tid];
        }
        // zero k-pairs 25..31 (k rows 50..63; MFMA pad — avoid NaN*0)
        for (int i = tid; i < 1024; i += 256) {
            const int n = i >> 3, pr = 24 + (i & 7);
            if (pr >= 25)
                *(unsigned*)((char*)Zt + ((n*128 + pr*4) ^ ZSWZ(n))) = 0u;
        }
    }
    __syncthreads();

    const float* mb = WvoSh + (lane & 3)*64;   // this lane's 4 rows of WvWo
    W_DECL(mb);

    // ---- process: reg proj (butterfly) -> token-pair pack (xor 32) -> Zt
    #pragma unroll
    for (int i = 0; i < 7; ++i) {
        const int t = t0 + 8*i;
        if (t >= NT) vv[i] = make_float4(0.f,0.f,0.f,0.f);
        PROJ_BFLY(vv[i], y0, y1, y2, y3);
        float4 sel;
        if      (r == 0) sel = y0;
        else if (r == 1) sel = y1;
        else if (r == 2) sel = y2;
        else             sel = y3;
        float4 po;
        po.x = __shfl_xor(sel.x, 32); po.y = __shfl_xor(sel.y, 32);
        po.z = __shfl_xor(sel.z, 32); po.w = __shfl_xor(sel.w, 32);
        if (lane < 32) {                      // own=even token, po=odd token
            const int n0 = (f4 >> 2)*16 + r*4;
            const int pair = wv + 4*i;
            *(unsigned*)((char*)Zt + (((n0+0)*128 + pair*4) ^ ZSWZ(n0+0))) = pk2(sel.x, po.x);
            *(unsigned*)((char*)Zt + (((n0+1)*128 + pair*4) ^ ZSWZ(n0+1))) = pk2(sel.y, po.y);
            *(unsigned*)((char*)Zt + (((n0+2)*128 + pair*4) ^ ZSWZ(n0+2))) = pk2(sel.z, po.z);
            *(unsigned*)((char*)Zt + (((n0+3)*128 + pair*4) ^ ZSWZ(n0+3))) = pk2(sel.w, po.w);
        }
    }
    __syncthreads();

    // MFMA + direct global store (4 rows x 64B full sectors per instruction)
    float* obase = out + (size_t)b*NT*TOKS + h*HSL + kc*128;
    #pragma unroll
    for (int nt2 = 0; nt2 < 8; ++nt2) {
        const int n    = nt2*16 + (lane & 15);
        const int swzn = ZSWZ(n);
        const bf16x8 bf0 = *(const bf16x8*)((const char*)Zt + ((n*128 +      (lane >> 4)*16) ^ swzn));
        const bf16x8 bf1 = *(const bf16x8*)((const char*)Zt + ((n*128 + 64 + (lane >> 4)*16) ^ swzn));
        f32x4 acc = (f32x4){0.f, 0.f, 0.f, 0.f};
        acc = __builtin_amdgcn_mfma_f32_16x16x32_bf16(af0, bf0, acc, 0, 0, 0);
        acc = __builtin_amdgcn_mfma_f32_16x16x32_bf16(af1, bf1, acc, 0, 0, 0);
        const float bias = bvoSh[n & 15];
        #pragma unroll
        for (int r2 = 0; r2 < 4; ++r2) {
            const int row = wv*16 + (lane >> 4)*4 + r2;
            if (row < NT) obase[(size_t)row*TOKS + n] = acc[r2] + bias;
        }
    }
}

extern "C" void kernel_launch(void* const* d_in, const int* in_sizes, int n_in,
                              void* d_out, int out_size, void* d_ws, size_t ws_size,
                              hipStream_t stream) {
    const float* v  = (const float*)d_in[0];
    const float* k  = (const float*)d_in[1];
    const float* q  = (const float*)d_in[2];
    const float* Wq = (const float*)d_in[3];
    const float* bq = (const float*)d_in[4];
    const float* Wk = (const float*)d_in[5];
    const float* bk = (const float*)d_in[6];   // softmax-row-invariant; unused
    const float* Wv = (const float*)d_in[7];
    const float* bv = (const float*)d_in[8];
    const float* Wo = (const float*)d_in[9];
    const float* bo = (const float*)d_in[10];
    (void)bk; (void)in_sizes; (void)n_in; (void)out_size;

    float* outp  = (float*)d_out;
    float* attnp = outp + (size_t)32 * 49 * 16384;      // out | attn concat
    float* ws1   = (float*)d_ws;

    const size_t need4 = (size_t)2048*SLOT*4 + (size_t)512*4096*2;
    if (ws_size >= need4) {
        ushort* ws2 = (ushort*)(ws1 + (size_t)2048*SLOT);
        k_scores<4,2><<<dim3(2048), dim3(256), 0, stream>>>(q, k, Wq, bq, Wk, ws1);
        k_softmax<4> <<<dim3(512),  dim3(256), 0, stream>>>(ws1, attnp, ws2);
        k_out        <<<dim3(4096), dim3(256), 0, stream>>>(v, Wv, bv, Wo, bo, ws2, outp);
    } else {
        ushort* ws2 = (ushort*)(ws1 + (size_t)1024*SLOT);
        k_scores<2,1><<<dim3(1024), dim3(256), 0, stream>>>(q, k, Wq, bq, Wk, ws1);
        k_softmax<2> <<<dim3(512),  dim3(256), 0, stream>>>(ws1, attnp, ws2);
        k_out        <<<dim3(4096), dim3(256), 0, stream>>>(v, Wv, bv, Wo, bo, ws2, outp);
    }
}

// Round 10
// 131.241 us; speedup vs baseline: 1.2097x; 1.2097x over previous
//
#include <hip/hip_runtime.h>
#include <hip/hip_bf16.h>

// LFA_self — 3-kernel pipeline for MI355X (round 10).
// scores = Xq (Wq Wk^T) Xk^T + g(t2); out = attn . (Xv (Wv Wo)) + (bv Wo + bo).
// Round-10: (a) revert inline cvt_pk (m240-consistent regression) to manual
// RNE pack; (b) projection = quarter-output scheme: thread owns 4 columns of
// M^T in registers, 64 straight-line fmaf per unit, NO cross-lane shuffles
// (r<=9 used 32 DS-pipe shfl per item in dependency chains); (c) SPLIT=8:
// per-block chain is a single {load, project, barrier, 16 MFMA, store}.

#define NT 49
#define TOKS 16384
#define HSL 1024
#define SLOT 3200            // floats per partial slot: 49x64 scores + 64 g-tail
#define ZSWZ(n) (((((n) & 7) ^ (((n) >> 3) & 7))) << 4)

typedef __attribute__((ext_vector_type(8))) short bf16x8;
typedef __attribute__((ext_vector_type(4))) float f32x4;

__device__ __forceinline__ ushort f2bf(float f) {
    union { float f; unsigned u; } v; v.f = f;
    return (ushort)((v.u + 0x7fffu + ((v.u >> 16) & 1u)) >> 16);   // RNE
}
__device__ __forceinline__ unsigned pk2(float lo, float hi) {
    return (unsigned)f2bf(lo) | ((unsigned)f2bf(hi) << 16);
}
// 16-term dot: x (16 ch as 4 float4) . w-row (4 float4)
__device__ __forceinline__ float qdot(float4 x0, float4 x1, float4 x2, float4 x3,
                                      float4 wa, float4 wb, float4 wc, float4 wd) {
    float s =      x0.x*wa.x;
    s = fmaf(x0.y, wa.y, s); s = fmaf(x0.z, wa.z, s); s = fmaf(x0.w, wa.w, s);
    s = fmaf(x1.x, wb.x, s); s = fmaf(x1.y, wb.y, s); s = fmaf(x1.z, wb.z, s);
    s = fmaf(x1.w, wb.w, s);
    s = fmaf(x2.x, wc.x, s); s = fmaf(x2.y, wc.y, s); s = fmaf(x2.z, wc.z, s);
    s = fmaf(x2.w, wc.w, s);
    s = fmaf(x3.x, wd.x, s); s = fmaf(x3.y, wd.y, s); s = fmaf(x3.z, wd.z, s);
    s = fmaf(x3.w, wd.w, s);
    return s;
}

// W preload: 16 named float4 = 4 rows (c2 = 4r..4r+3) of a transposed 16x16
// weight (row-major W^T, each row = 16 c-weights)
#define W_DECL(mb) \
    const float4 W00 = *(const float4*)((mb)+ 0), W01 = *(const float4*)((mb)+ 4), \
                 W02 = *(const float4*)((mb)+ 8), W03 = *(const float4*)((mb)+12), \
                 W10 = *(const float4*)((mb)+16), W11 = *(const float4*)((mb)+20), \
                 W12 = *(const float4*)((mb)+24), W13 = *(const float4*)((mb)+28), \
                 W20 = *(const float4*)((mb)+32), W21 = *(const float4*)((mb)+36), \
                 W22 = *(const float4*)((mb)+40), W23 = *(const float4*)((mb)+44), \
                 W30 = *(const float4*)((mb)+48), W31 = *(const float4*)((mb)+52), \
                 W32 = *(const float4*)((mb)+56), W33 = *(const float4*)((mb)+60)

// ===== K1: partial scores, grid (b,h,s)=512*SPLIT, 256 thr =================
template<int SPLIT, int LOG2S>
__global__ __launch_bounds__(256, 2) void k_scores(
    const float* __restrict__ qin, const float* __restrict__ kin,
    const float* __restrict__ Wq, const float* __restrict__ bq,
    const float* __restrict__ Wk, float* __restrict__ ws1)
{
    __shared__ ushort bufA[64*128];   // Yq bf16, 256B rows, XOR-swizzled
    __shared__ ushort bufB[64*128];   // Xk bf16, swizzled
    __shared__ float  Msh[256];       // (Wq Wk^T)^T : Msh[c2*16+c1]
    __shared__ float  wkbqSh[16];     // Wk bq
    __shared__ float  gSh[64];

    const int tid  = threadIdx.x;
    const int lane = tid & 63;
    const int wv   = tid >> 6;        // 0..3
    const int s    = blockIdx.x & (SPLIT - 1);
    const int h    = (blockIdx.x >> LOG2S) & 15;
    const int b    = blockIdx.x >> (LOG2S + 4);

    const float* qbase = qin + (size_t)b*NT*TOKS + h*HSL + s*(1024/SPLIT);
    const float* kbase = kin + (size_t)b*NT*TOKS + h*HSL + s*(1024/SPLIT);

    const int f4 = tid & 31;          // k-item column group (invariant)
    const int t0 = tid >> 5;          // base token
    const int si = (tid >> 2) & 7;    // q-unit column group (invariant)
    const int rq = tid & 3;           // q-unit output quarter (invariant)

    constexpr int NC = 8 / SPLIT;

    // ---- issue chunk-0 loads FIRST (latency hides under init)
    float4 kv[7];
    {
        const float* kp = kbase + f4*4;
        #pragma unroll
        for (int i = 0; i < 7; ++i) {
            const int t = t0 + 8*i; const int tc = t < 48 ? t : 48;
            kv[i] = *(const float4*)(kp + (size_t)tc*TOKS);
        }
    }
    float4 xa0, xa1, xa2, xa3;
    {
        const float* qc = qbase + si*16 + (size_t)t0*TOKS;
        xa0 = *(const float4*)(qc);
        xa1 = *(const float4*)(qc + 4);
        xa2 = *(const float4*)(qc + 8);
        xa3 = *(const float4*)(qc + 12);
    }

    {   // init: zero both MFMA buffers (pad rows 49..63 must be 0), weights
        unsigned* z0 = (unsigned*)bufA; unsigned* z1 = (unsigned*)bufB;
        #pragma unroll
        for (int i = 0; i < 16; ++i) { z0[tid + 256*i] = 0u; z1[tid + 256*i] = 0u; }
        const int c1 = tid >> 4, c2 = tid & 15;
        float m = 0.f;
        #pragma unroll
        for (int f = 0; f < 16; ++f) m += Wq[c1*16+f] * Wk[c2*16+f];
        Msh[c2*16 + c1] = m;                       // transposed store
        if (tid < 16) {
            float wb = 0.f;
            #pragma unroll
            for (int g = 0; g < 16; ++g) wb += Wk[tid*16+g] * bq[g];
            wkbqSh[tid] = wb;
        }
        if (tid < 64) gSh[tid] = 0.f;
    }
    __syncthreads();

    W_DECL(Msh + rq*64);              // this lane's 4 output rows of M^T

    f32x4 accS[4];
    #pragma unroll
    for (int nt = 0; nt < 4; ++nt) accS[nt] = (f32x4){0.f,0.f,0.f,0.f};

    for (int kc = 0; kc < NC; ++kc) {
        if (kc > 0) {                 // fallback paths (SPLIT<8): refill batches
            const float* kp = kbase + kc*128 + f4*4;
            #pragma unroll
            for (int i = 0; i < 7; ++i) {
                const int t = t0 + 8*i; const int tc = t < 48 ? t : 48;
                kv[i] = *(const float4*)(kp + (size_t)tc*TOKS);
            }
            const float* qc = qbase + kc*128 + si*16 + (size_t)t0*TOKS;
            xa0 = *(const float4*)(qc);
            xa1 = *(const float4*)(qc + 4);
            xa2 = *(const float4*)(qc + 8);
            xa3 = *(const float4*)(qc + 12);
        }
        // ---- k: convert + write bufB (overlaps q-unit-0 latency)
        #pragma unroll
        for (int i = 0; i < 7; ++i) {
            const int t = t0 + 8*i;
            float4 xk = kv[i];
            if (t >= NT) xk = make_float4(0.f,0.f,0.f,0.f);
            uint2 w; w.x = pk2(xk.x, xk.y); w.y = pk2(xk.z, xk.w);
            *(uint2*)((char*)bufB + ((t*256 + f4*8) ^ ((t & 7) << 4))) = w;
            const float* wb = wkbqSh + (f4 & 3)*4;
            const float pg = xk.x*wb[0] + xk.y*wb[1] + xk.z*wb[2] + xk.w*wb[3];
            if (pg != 0.f) atomicAdd(&gSh[t], pg);   // bq==0 -> never fires
        }
        // ---- q units: 2-deep pipeline {load next, project current}
        #pragma unroll
        for (int i = 0; i < 7; ++i) {
            float4 xb0 = xa0, xb1 = xa1, xb2 = xa2, xb3 = xa3;
            if (i < 6) {
                const int tn = t0 + 8*(i+1); const int tc = tn < 48 ? tn : 48;
                const float* qc = qbase + kc*128 + si*16 + (size_t)tc*TOKS;
                xb0 = *(const float4*)(qc);
                xb1 = *(const float4*)(qc + 4);
                xb2 = *(const float4*)(qc + 8);
                xb3 = *(const float4*)(qc + 12);
            }
            const int t = t0 + 8*i;
            if (t < NT) {
                const float o0 = qdot(xa0,xa1,xa2,xa3, W00,W01,W02,W03);
                const float o1 = qdot(xa0,xa1,xa2,xa3, W10,W11,W12,W13);
                const float o2 = qdot(xa0,xa1,xa2,xa3, W20,W21,W22,W23);
                const float o3 = qdot(xa0,xa1,xa2,xa3, W30,W31,W32,W33);
                uint2 w; w.x = pk2(o0, o1); w.y = pk2(o2, o3);
                *(uint2*)((char*)bufA + ((t*256 + si*32 + rq*8) ^ ((t & 7) << 4))) = w;
            }
            xa0 = xb0; xa1 = xb1; xa2 = xb2; xa3 = xb3;
        }
        __syncthreads();
        // ---- MFMA: K-chunk 128 = 4 ksteps (proven path, unchanged)
        #pragma unroll
        for (int ks = 0; ks < 4; ++ks) {
            const int ra  = wv*16 + (lane & 15);
            const int abo = (ra*256 + (ks*32 + (lane >> 4)*8)*2) ^ ((ra & 7) << 4);
            const bf16x8 af = *(const bf16x8*)((const char*)bufA + abo);
            #pragma unroll
            for (int nt = 0; nt < 4; ++nt) {
                const int rb  = nt*16 + (lane & 15);
                const int bbo = (rb*256 + (ks*32 + (lane >> 4)*8)*2) ^ ((rb & 7) << 4);
                const bf16x8 bf = *(const bf16x8*)((const char*)bufB + bbo);
                accS[nt] = __builtin_amdgcn_mfma_f32_16x16x32_bf16(af, bf, accS[nt], 0, 0, 0);
            }
        }
        if (kc + 1 < NC) __syncthreads();
    }

    float* slot = ws1 + (size_t)blockIdx.x * SLOT;
    #pragma unroll
    for (int nt = 0; nt < 4; ++nt) {
        const int col = nt*16 + (lane & 15);
        #pragma unroll
        for (int rr = 0; rr < 4; ++rr) {
            const int row = wv*16 + (lane >> 4)*4 + rr;
            if (row < NT) slot[row*64 + col] = accS[nt][rr];
        }
    }
    if (tid < 64) slot[3136 + tid] = gSh[tid];
}

// ===== K2: reduce + softmax, grid (b,h)=512, 256 thr =======================
template<int SPLIT>
__global__ __launch_bounds__(256, 2) void k_softmax(
    const float* __restrict__ ws1, float* __restrict__ attnp,
    ushort* __restrict__ ws2)
{
    __shared__ float sS[NT*69];
    __shared__ float sG[64];
    const int tid = threadIdx.x;
    const float* base = ws1 + (size_t)blockIdx.x * SPLIT * SLOT;

    for (int p = tid; p < 784; p += 256) {
        const int row = p >> 4, c4 = (p & 15) * 4;
        float4 acc = *(const float4*)(base + row*64 + c4);
        #pragma unroll
        for (int s = 1; s < SPLIT; ++s) {
            const float4 a = *(const float4*)(base + s*SLOT + row*64 + c4);
            acc.x += a.x; acc.y += a.y; acc.z += a.z; acc.w += a.w;
        }
        sS[row*69 + c4 + 0] = acc.x;
        sS[row*69 + c4 + 1] = acc.y;
        sS[row*69 + c4 + 2] = acc.z;
        sS[row*69 + c4 + 3] = acc.w;
    }
    if (tid < 64) {
        float g = base[3136 + tid];
        #pragma unroll
        for (int s = 1; s < SPLIT; ++s) g += base[s*SLOT + 3136 + tid];
        sG[tid] = g;
    }
    __syncthreads();

    if (tid < NT) {
        float mx = -1e30f;
        for (int j = 0; j < NT; ++j) {
            const float v = (sS[tid*69 + j] + sG[j]) * 0.03125f;
            sS[tid*69 + j] = v;
            mx = fmaxf(mx, v);
        }
        float ssum = 0.f;
        for (int j = 0; j < NT; ++j) {
            const float e = __expf(sS[tid*69 + j] - mx);
            sS[tid*69 + j] = e; ssum += e;
        }
        const float inv = 1.0f / ssum;
        for (int j = 0; j < NT; ++j) sS[tid*69 + j] *= inv;
    }
    __syncthreads();

    float* ab = attnp + (size_t)blockIdx.x * (NT*NT);
    for (int p = tid; p < NT*NT; p += 256) {
        const int t = p / NT, j = p - t*NT;
        ab[p] = sS[t*69 + j];
    }
    ushort* w2 = ws2 + (size_t)blockIdx.x * 4096;   // 64x64 bf16, zero-padded
    for (int p = tid; p < 4096; p += 256) {
        const int t = p >> 6, j = p & 63;
        const float v = (t < NT && j < NT) ? sS[t*69 + j] : 0.f;
        w2[p] = f2bf(v);
    }
}

// ===== K3: out = attn.Z + bvo, grid (b,h,kc)=4096, 256 thr =================
__global__ __launch_bounds__(256, 2) void k_out(
    const float* __restrict__ vin,
    const float* __restrict__ Wv, const float* __restrict__ bv,
    const float* __restrict__ Wo, const float* __restrict__ bo,
    const ushort* __restrict__ ws2, float* __restrict__ out)
{
    __shared__ unsigned Zt[4096];     // Z^T pair-packed: [128 n][32 kpair] u32
    __shared__ float WvoSh[256];      // (Wv Wo)^T
    __shared__ float bvoSh[16];

    const int tid  = threadIdx.x;
    const int lane = tid & 63;
    const int wv   = tid >> 6;        // 0..3 -> M-tile (token rows)
    const int kc   = blockIdx.x & 7;
    const int h    = (blockIdx.x >> 3) & 15;
    const int b    = blockIdx.x >> 7;
    const float* vbase = vin + (size_t)b*NT*TOKS + h*HSL;

    const int si = (tid >> 2) & 7;    // unit column group (invariant)
    const int rq = tid & 3;           // unit output quarter (invariant)
    const int t0 = tid >> 5;          // base token

    // ---- issue global loads first (attn A-fragments + v unit 0)
    const ushort* w2 = ws2 + ((size_t)(blockIdx.x >> 3)) * 4096;
    const int ra = wv*16 + (lane & 15);
    const bf16x8 af0 = *(const bf16x8*)(w2 + ra*64 +      (lane >> 4)*8);
    const bf16x8 af1 = *(const bf16x8*)(w2 + ra*64 + 32 + (lane >> 4)*8);
    float4 xa0, xa1, xa2, xa3;
    {
        const float* vc = vbase + kc*128 + si*16 + (size_t)t0*TOKS;
        xa0 = *(const float4*)(vc);
        xa1 = *(const float4*)(vc + 4);
        xa2 = *(const float4*)(vc + 8);
        xa3 = *(const float4*)(vc + 12);
    }

    {   // init: weights (transposed), bias, full Zt zero (covers t=49.. pad)
        const int c1 = tid >> 4, c2 = tid & 15;
        float wvo = 0.f;
        #pragma unroll
        for (int f = 0; f < 16; ++f) wvo += Wv[c1*16+f] * Wo[f*16+c2];
        WvoSh[c2*16 + c1] = wvo;                  // transposed store
        if (tid < 16) {
            float s2 = 0.f;
            #pragma unroll
            for (int g = 0; g < 16; ++g) s2 += bv[g]*Wo[g*16+tid];
            bvoSh[tid] = s2 + bo[tid];
        }
        #pragma unroll
        for (int i = 0; i < 16; ++i) Zt[tid + 256*i] = 0u;
    }
    __syncthreads();

    W_DECL(WvoSh + rq*64);

    // ---- units: {load next, project current, 4 u16 writes into Zt}
    #pragma unroll
    for (int i = 0; i < 7; ++i) {
        float4 xb0 = xa0, xb1 = xa1, xb2 = xa2, xb3 = xa3;
        if (i < 6) {
            const int tn = t0 + 8*(i+1); const int tc = tn < 48 ? tn : 48;
            const float* vc = vbase + kc*128 + si*16 + (size_t)tc*TOKS;
            xb0 = *(const float4*)(vc);
            xb1 = *(const float4*)(vc + 4);
            xb2 = *(const float4*)(vc + 8);
            xb3 = *(const float4*)(vc + 12);
        }
        const int t = t0 + 8*i;
        if (t < NT) {
            const float o0 = qdot(xa0,xa1,xa2,xa3, W00,W01,W02,W03);
            const float o1 = qdot(xa0,xa1,xa2,xa3, W10,W11,W12,W13);
            const float o2 = qdot(xa0,xa1,xa2,xa3, W20,W21,W22,W23);
            const float o3 = qdot(xa0,xa1,xa2,xa3, W30,W31,W32,W33);
            const int n0 = si*16 + rq*4;
            const int pb = (t >> 1)*4, hb = (t & 1)*2;
            *(ushort*)((char*)Zt + ((((n0+0)*128 + pb) ^ ZSWZ(n0+0)) + hb)) = f2bf(o0);
            *(ushort*)((char*)Zt + ((((n0+1)*128 + pb) ^ ZSWZ(n0+1)) + hb)) = f2bf(o1);
            *(ushort*)((char*)Zt + ((((n0+2)*128 + pb) ^ ZSWZ(n0+2)) + hb)) = f2bf(o2);
            *(ushort*)((char*)Zt + ((((n0+3)*128 + pb) ^ ZSWZ(n0+3)) + hb)) = f2bf(o3);
        }
        xa0 = xb0; xa1 = xb1; xa2 = xb2; xa3 = xb3;
    }
    __syncthreads();

    // MFMA + direct global store (4 rows x 64B full sectors per instruction)
    float* obase = out + (size_t)b*NT*TOKS + h*HSL + kc*128;
    #pragma unroll
    for (int nt2 = 0; nt2 < 8; ++nt2) {
        const int n    = nt2*16 + (lane & 15);
        const int swzn = ZSWZ(n);
        const bf16x8 bf0 = *(const bf16x8*)((const char*)Zt + ((n*128 +      (lane >> 4)*16) ^ swzn));
        const bf16x8 bf1 = *(const bf16x8*)((const char*)Zt + ((n*128 + 64 + (lane >> 4)*16) ^ swzn));
        f32x4 acc = (f32x4){0.f, 0.f, 0.f, 0.f};
        acc = __builtin_amdgcn_mfma_f32_16x16x32_bf16(af0, bf0, acc, 0, 0, 0);
        acc = __builtin_amdgcn_mfma_f32_16x16x32_bf16(af1, bf1, acc, 0, 0, 0);
        const float bias = bvoSh[n & 15];
        #pragma unroll
        for (int r2 = 0; r2 < 4; ++r2) {
            const int row = wv*16 + (lane >> 4)*4 + r2;
            if (row < NT) obase[(size_t)row*TOKS + n] = acc[r2] + bias;
        }
    }
}

extern "C" void kernel_launch(void* const* d_in, const int* in_sizes, int n_in,
                              void* d_out, int out_size, void* d_ws, size_t ws_size,
                              hipStream_t stream) {
    const float* v  = (const float*)d_in[0];
    const float* k  = (const float*)d_in[1];
    const float* q  = (const float*)d_in[2];
    const float* Wq = (const float*)d_in[3];
    const float* bq = (const float*)d_in[4];
    const float* Wk = (const float*)d_in[5];
    const float* bk = (const float*)d_in[6];   // softmax-row-invariant; unused
    const float* Wv = (const float*)d_in[7];
    const float* bv = (const float*)d_in[8];
    const float* Wo = (const float*)d_in[9];
    const float* bo = (const float*)d_in[10];
    (void)bk; (void)in_sizes; (void)n_in; (void)out_size;

    float* outp  = (float*)d_out;
    float* attnp = outp + (size_t)32 * 49 * 16384;      // out | attn concat
    float* ws1   = (float*)d_ws;

    const size_t need8 = (size_t)4096*SLOT*4 + (size_t)512*4096*2;
    const size_t need4 = (size_t)2048*SLOT*4 + (size_t)512*4096*2;
    if (ws_size >= need8) {
        ushort* ws2 = (ushort*)(ws1 + (size_t)4096*SLOT);
        k_scores<8,3><<<dim3(4096), dim3(256), 0, stream>>>(q, k, Wq, bq, Wk, ws1);
        k_softmax<8> <<<dim3(512),  dim3(256), 0, stream>>>(ws1, attnp, ws2);
        k_out        <<<dim3(4096), dim3(256), 0, stream>>>(v, Wv, bv, Wo, bo, ws2, outp);
    } else if (ws_size >= need4) {
        ushort* ws2 = (ushort*)(ws1 + (size_t)2048*SLOT);
        k_scores<4,2><<<dim3(2048), dim3(256), 0, stream>>>(q, k, Wq, bq, Wk, ws1);
        k_softmax<4> <<<dim3(512),  dim3(256), 0, stream>>>(ws1, attnp, ws2);
        k_out        <<<dim3(4096), dim3(256), 0, stream>>>(v, Wv, bv, Wo, bo, ws2, outp);
    } else {
        ushort* ws2 = (ushort*)(ws1 + (size_t)1024*SLOT);
        k_scores<2,1><<<dim3(1024), dim3(256), 0, stream>>>(q, k, Wq, bq, Wk, ws1);
        k_softmax<2> <<<dim3(512),  dim3(256), 0, stream>>>(ws1, attnp, ws2);
        k_out        <<<dim3(4096), dim3(256), 0, stream>>>(v, Wv, bv, Wo, bo, ws2, outp);
    }
}